// Round 7
// baseline (178.285 us; speedup 1.0000x reference)
//
#include <hip/hip_runtime.h>
#include <hip/hip_fp16.h>

// BackProjectionLinear: out[b,p] = sum_d apod[d] * lerp(sino[b,d], k[p,d], a[p,d]) / 63.5
// B=4, N_DET=128, N_T=2048, pixels=65536.
//
// R16 = R15 structure with the two parameter bugs fixed.
// R15b post-mortem: __launch_bounds__(1024,4) made the compiler cap VGPR at
// 64 -> ~45MB scratch spill (WRITE 62MB vs 17), VALUBusy 4%, 83us. And
// octet-major block order scattered each octet's 16 blocks across all 8
// XCDs -> ws16 slices re-fetched per XCD (FETCH +16MB). Fixes:
//  - __launch_bounds__(1024) only: launchability forces VGPR<=128; kernel
//    needs ~90-100 -> no spill, no artificial cap.
//  - octet = bid&15, tile = bid>>4 (R11 order): all 16 blocks of an octet
//    share bid%8 -> same XCD -> ws16 slice fetched once per XCD.
// Structure (unchanged): block = octet x 4096px, 1024 thr, 128KB LDS = the
// ENTIRE octet staged once, ONE barrier; per thread 4 px, each px = one
// full 64B lut line (4 x fv4 nt loads), 2-px double-buffer paced by counted
// vmcnt(4)/vmcnt(0) fences; LDS gathers ride lgkmcnt so the lut vmcnt
// stream never idles. 256 blocks = 1/CU. atomic emit (R9: atomics==stores).
// Canaries: VGPR 96-128, WRITE ~17MB, FETCH ~70MB.

#define NB      4
#define NDET    128
#define NT      2048
#define NPIX    65536
#define OCT     8                    // dets per block
#define PTILE   4096                 // px per block
#define THR     1024
#define PXT     (PTILE / THR)        // 4 px per thread

typedef float fv4 __attribute__((ext_vector_type(4)));

// ---- pass 1: sino fp32[4][128][2048] -> ws16[det][t] = 8B (4 batches fp16) ----
__global__ __launch_bounds__(256)
void cvt_kernel(const float* __restrict__ sino, uint2* __restrict__ ws16) {
    const int id = blockIdx.x * 256 + threadIdx.x;     // det*NT + t
    float v0 = sino[id];
    float v1 = sino[id + NDET * NT];
    float v2 = sino[id + 2 * NDET * NT];
    float v3 = sino[id + 3 * NDET * NT];
    __half2 h01 = __floats2half2_rn(v0, v1);
    __half2 h23 = __floats2half2_rn(v2, v3);
    uint2 u;
    u.x = *(const unsigned*)&h01;
    u.y = *(const unsigned*)&h23;
    ws16[id] = u;
}

// ---- pass 2: one octet per block, staged once, zero inner barriers ----
__global__ __launch_bounds__(THR)
void bp_oct(const uint2* __restrict__ ws16,
            const float* __restrict__ lut,
            float* __restrict__ out) {
    __shared__ uint2 lds[OCT * NT];                    // 128 KB

    const int tid   = threadIdx.x;
    const int octet = blockIdx.x & 15;                 // all 16 tiles of an octet share bid%8 -> one XCD
    const int tile  = blockIdx.x >> 4;
    const int d0    = octet * OCT;
    const int px0   = tile * PTILE;

    float apod[OCT];
#pragma unroll
    for (int j = 0; j < OCT; ++j) {
        float x = (float)(d0 + j) * (6.28318530717958647692f / 127.0f);
        apod[j] = 0.5f - 0.5f * __cosf(x);
    }

    // ---- stage the whole octet: 128KB contiguous, pure uint4 copy ----
    {
        const uint4* src = (const uint4*)(ws16 + (size_t)d0 * NT);
        uint4* dst = (uint4*)lds;
#pragma unroll
        for (int r = 0; r < 8; ++r) dst[tid + r * THR] = src[tid + r * THR];
    }
    __syncthreads();                                   // the ONLY barrier

    // thread's lut lines: px = px0 + tid + i*THR; 64B line at fv4 offset
    // px*64 + octet*4. Per-i delta = THR*64 = 65536 fv4.
    const fv4* lbase = (const fv4*)lut
                     + (size_t)(px0 + tid) * (NDET / 2) + octet * 4;

    float acc[PXT][NB];
#pragma unroll
    for (int i = 0; i < PXT; ++i)
#pragma unroll
        for (int b = 0; b < NB; ++b) acc[i][b] = 0.0f;

    // ---- prologue: px0 + px1 lut lines in flight (8 wave-loads) ----
    fv4 lv[2][4];
#pragma unroll
    for (int q = 0; q < 4; ++q)
        lv[0][q] = __builtin_nontemporal_load(lbase + q);
#pragma unroll
    for (int q = 0; q < 4; ++q)
        lv[1][q] = __builtin_nontemporal_load(lbase + 65536 + q);

    // ---- main loop: fully unrolled; gathers are lgkmcnt so vmcnt stream
    //      keeps >= 4 lut loads in flight until the tail ----
#pragma unroll
    for (int i = 0; i < PXT; ++i) {
        if (i + 1 < PXT) {
            asm volatile("s_waitcnt vmcnt(4)" ::: "memory");   // px i's 4 done
        } else {
            asm volatile("s_waitcnt vmcnt(0)" ::: "memory");   // tail drain
        }
        __builtin_amdgcn_sched_barrier(0);

#pragma unroll
        for (int q = 0; q < 4; ++q) {
            const fv4 Le = lv[i & 1][q];
#pragma unroll
            for (int h = 0; h < 2; ++h) {
                const int dl = 2 * q + h;
                float kf = h ? Le.z : Le.x;
                float af = h ? Le.w : Le.y;
                int   k  = (int)kf;
                bool  valid = (unsigned)k < (unsigned)(NT - 1);
                int   k0 = valid ? k : 0;
                float w  = valid ? apod[dl] : 0.0f;
                uint2 e0 = lds[dl * NT + k0];
                uint2 e1 = lds[dl * NT + k0 + 1];
                __half2 a01 = *(__half2*)&e0.x, a23 = *(__half2*)&e0.y;
                __half2 b01 = *(__half2*)&e1.x, b23 = *(__half2*)&e1.y;
                __half2 a2  = __float2half2_rn(af);
                __half2 s01 = __hfma2(a2, __hsub2(b01, a01), a01);
                __half2 s23 = __hfma2(a2, __hsub2(b23, a23), a23);
                float2 f01 = __half22float2(s01);
                float2 f23 = __half22float2(s23);
                acc[i][0] = fmaf(w, f01.x, acc[i][0]);
                acc[i][1] = fmaf(w, f01.y, acc[i][1]);
                acc[i][2] = fmaf(w, f23.x, acc[i][2]);
                acc[i][3] = fmaf(w, f23.y, acc[i][3]);
            }
        }

        // refill the buffer just consumed with px i+2's line
        if (i + 2 < PXT) {
#pragma unroll
            for (int q = 0; q < 4; ++q)
                lv[i & 1][q] = __builtin_nontemporal_load(
                    lbase + (size_t)(i + 2) * 65536 + q);
        }
    }

    // ---- emit: 16 octet-blocks accumulate per output ----
    const float inv_norm = 1.0f / 63.5f;               // sum(apod) == 63.5 exactly
#pragma unroll
    for (int i = 0; i < PXT; ++i) {
        const int px = px0 + tid + i * THR;
#pragma unroll
        for (int b = 0; b < NB; ++b)
            atomicAdd(&out[(size_t)b * NPIX + px], acc[i][b] * inv_norm);
    }
}

// ---- fallback (ws too small): fp32 staging + cvt in-kernel ----
__global__ __launch_bounds__(512, 4)
void bp_fallback(const float* __restrict__ sino,
                 const float* __restrict__ lut,
                 float* __restrict__ out) {
    __shared__ __half2 lds[4][NT];
    const int tid   = threadIdx.x;
    const int octet = blockIdx.x & 15;
    const int tile  = blockIdx.x >> 4;
    const int d0    = octet * 8;
    const int px0   = tile * 1024;
    float apod[8];
#pragma unroll
    for (int j = 0; j < 8; ++j) {
        float x = (float)(d0 + j) * (6.28318530717958647692f / 127.0f);
        apod[j] = 0.5f - 0.5f * __cosf(x);
    }
    float4 L[2][4];
#pragma unroll
    for (int i = 0; i < 2; ++i) {
        const float4* lq = (const float4*)
            (lut + ((size_t)(px0 + tid + i * 512) * NDET + d0) * 2);
#pragma unroll
        for (int q = 0; q < 4; ++q) L[i][q] = lq[q];
    }
    float acc[2][NB];
#pragma unroll
    for (int i = 0; i < 2; ++i)
#pragma unroll
        for (int b = 0; b < NB; ++b) acc[i][b] = 0.0f;
    const float4* s4 = (const float4*)sino;
    for (int ph = 0; ph < 4; ++ph) {
        const int b0  = (ph >> 1) * 2;
        const int dh  = ph & 1;
        const int dg0 = d0 + dh * 4;
        if (ph) __syncthreads();
        for (int f = tid; f < 4 * (NT / 4); f += 512) {
            int dl = f >> 9;
            int t4 = f & 511;
            size_t row = ((size_t)b0 * NDET + dg0 + dl) * (NT / 4) + t4;
            float4 ve = s4[row];
            float4 vo = s4[row + (size_t)NDET * (NT / 4)];
            __half2* dstp = &lds[dl][t4 * 4];
            dstp[0] = __floats2half2_rn(ve.x, vo.x);
            dstp[1] = __floats2half2_rn(ve.y, vo.y);
            dstp[2] = __floats2half2_rn(ve.z, vo.z);
            dstp[3] = __floats2half2_rn(ve.w, vo.w);
        }
        __syncthreads();
#pragma unroll
        for (int i = 0; i < 2; ++i) {
#pragma unroll
            for (int q2 = 0; q2 < 2; ++q2) {
                float4 Lq = L[i][dh * 2 + q2];
#pragma unroll
                for (int h = 0; h < 2; ++h) {
                    float kf = h ? Lq.z : Lq.x;
                    float af = h ? Lq.w : Lq.y;
                    int   dl = q2 * 2 + h;
                    int k = (int)kf;
                    bool valid = (unsigned)k < (unsigned)(NT - 1);
                    float w  = valid ? apod[dh * 4 + dl] : 0.0f;
                    int  k0  = valid ? k : 0;
                    __half2 s0v = lds[dl][k0];
                    __half2 s1v = lds[dl][k0 + 1];
                    __half2 a2  = __float2half2_rn(af);
                    __half2 sk  = __hfma2(a2, __hsub2(s1v, s0v), s0v);
                    float2  fv  = __half22float2(sk);
                    acc[i][b0 + 0] = fmaf(w, fv.x, acc[i][b0 + 0]);
                    acc[i][b0 + 1] = fmaf(w, fv.y, acc[i][b0 + 1]);
                }
            }
        }
    }
    const float inv_norm = 1.0f / 63.5f;
#pragma unroll
    for (int i = 0; i < 2; ++i) {
        const int px = px0 + tid + i * 512;
#pragma unroll
        for (int b = 0; b < NB; ++b)
            atomicAdd(&out[(size_t)b * NPIX + px], acc[i][b] * inv_norm);
    }
}

extern "C" void kernel_launch(void* const* d_in, const int* in_sizes, int n_in,
                              void* d_out, int out_size, void* d_ws, size_t ws_size,
                              hipStream_t stream) {
    const float* sino = (const float*)d_in[0];
    const float* lut  = (const float*)d_in[1];
    float* out = (float*)d_out;

    (void)hipMemsetAsync(d_out, 0, (size_t)out_size * sizeof(float), stream);

    const size_t ws_needed = (size_t)NDET * NT * sizeof(uint2);   // 2 MB
    if (ws_size >= ws_needed) {
        uint2* ws16 = (uint2*)d_ws;
        cvt_kernel<<<dim3(NDET * NT / 256), dim3(256), 0, stream>>>(sino, ws16);
        // 16 octets x 16 tiles = 256 blocks x 1024 thr = exactly 1 block/CU
        bp_oct<<<dim3(256), dim3(THR), 0, stream>>>(ws16, lut, out);
    } else {
        bp_fallback<<<dim3(1024), dim3(512), 0, stream>>>(sino, lut, out);
    }
}

// Round 8
// 153.402 us; speedup vs baseline: 1.1622x; 1.1622x over previous
//
#include <hip/hip_runtime.h>
#include <hip/hip_fp16.h>

// BackProjectionLinear: out[b,p] = sum_d apod[d] * lerp(sino[b,d], k[p,d], a[p,d]) / 63.5
// B=4, N_DET=128, N_T=2048, pixels=65536.
//
// R17 = R15/R16 structure with the scratch-alloca bug fixed (rule #20).
// R16 post-mortem: VGPR stayed 64 with ~45MB scratch — lv[i&1][q] is
// runtime-indexed when SROA runs (before unroll), so the array was never
// promoted; asm memory-clobber fences blocked later store-forwarding. Not
// regalloc spill. Fix: hand-unrolled loop, ALL state in named fv4 scalars
// (p0..p3 / n0..n3 / acc0..acc3 / ap0..ap7) — zero local arrays. Plus
// amdgpu_waves_per_eu(4,4): LDS already caps at 1 block/CU (=4 waves/EU),
// pin the scheduler there -> 128-VGPR budget, no occupancy cost.
// Structure: block = octet x 4096px, 1024 thr, 128KB LDS = whole octet
// staged once, ONE barrier; px0/px1 lut lines issued BEFORE the stage copy
// (syncthreads drains them for free -> latency hidden under staging);
// px2/px3 issued under px0/px1 compute, paced by counted vmcnt(4)/vmcnt(0)
// fences. LDS gathers ride lgkmcnt so the vmcnt lut stream never idles.
// 256 blocks = 1/CU, octet = bid&15 (all 16 tiles of an octet on one XCD).
// Canaries: VGPR 90-128, WRITE ~17MB, FETCH ~68MB.

#define NB      4
#define NDET    128
#define NT      2048
#define NPIX    65536
#define OCT     8                    // dets per block
#define PTILE   4096                 // px per block
#define THR     1024
#define PXT     (PTILE / THR)        // 4 px per thread

typedef float fv4 __attribute__((ext_vector_type(4)));

// ---- pass 1: sino fp32[4][128][2048] -> ws16[det][t] = 8B (4 batches fp16) ----
__global__ __launch_bounds__(256)
void cvt_kernel(const float* __restrict__ sino, uint2* __restrict__ ws16) {
    const int id = blockIdx.x * 256 + threadIdx.x;     // det*NT + t
    float v0 = sino[id];
    float v1 = sino[id + NDET * NT];
    float v2 = sino[id + 2 * NDET * NT];
    float v3 = sino[id + 3 * NDET * NT];
    __half2 h01 = __floats2half2_rn(v0, v1);
    __half2 h23 = __floats2half2_rn(v2, v3);
    uint2 u;
    u.x = *(const unsigned*)&h01;
    u.y = *(const unsigned*)&h23;
    ws16[id] = u;
}

// one det: k/a from lut entry halves, taps from LDS, accumulate 4 batches
__device__ __forceinline__ void pair_accum(const uint2* lds, int dl,
                                           float kf, float af, float ap,
                                           fv4& acc) {
    int  k  = (int)kf;
    bool valid = (unsigned)k < (unsigned)(NT - 1);
    int  k0 = valid ? k : 0;
    float w = valid ? ap : 0.0f;
    uint2 e0 = lds[dl * NT + k0];
    uint2 e1 = lds[dl * NT + k0 + 1];
    __half2 a01 = *(__half2*)&e0.x, a23 = *(__half2*)&e0.y;
    __half2 b01 = *(__half2*)&e1.x, b23 = *(__half2*)&e1.y;
    __half2 a2  = __float2half2_rn(af);
    __half2 s01 = __hfma2(a2, __hsub2(b01, a01), a01);
    __half2 s23 = __hfma2(a2, __hsub2(b23, a23), a23);
    float2 f01 = __half22float2(s01);
    float2 f23 = __half22float2(s23);
    acc.x = fmaf(w, f01.x, acc.x);
    acc.y = fmaf(w, f01.y, acc.y);
    acc.z = fmaf(w, f23.x, acc.z);
    acc.w = fmaf(w, f23.y, acc.w);
}

// ---- pass 2: one octet per block, staged once, zero inner barriers ----
__global__ __launch_bounds__(THR) __attribute__((amdgpu_waves_per_eu(4, 4)))
void bp_oct(const uint2* __restrict__ ws16,
            const float* __restrict__ lut,
            float* __restrict__ out) {
    __shared__ uint2 lds[OCT * NT];                    // 128 KB

    const int tid   = threadIdx.x;
    const int octet = blockIdx.x & 15;                 // 16 tiles of an octet share bid%8 -> one XCD
    const int tile  = blockIdx.x >> 4;
    const int d0    = octet * OCT;
    const int px0   = tile * PTILE;

    const float C = 6.28318530717958647692f / 127.0f;
    const float ap0 = 0.5f - 0.5f * __cosf((float)(d0 + 0) * C);
    const float ap1 = 0.5f - 0.5f * __cosf((float)(d0 + 1) * C);
    const float ap2 = 0.5f - 0.5f * __cosf((float)(d0 + 2) * C);
    const float ap3 = 0.5f - 0.5f * __cosf((float)(d0 + 3) * C);
    const float ap4 = 0.5f - 0.5f * __cosf((float)(d0 + 4) * C);
    const float ap5 = 0.5f - 0.5f * __cosf((float)(d0 + 5) * C);
    const float ap6 = 0.5f - 0.5f * __cosf((float)(d0 + 6) * C);
    const float ap7 = 0.5f - 0.5f * __cosf((float)(d0 + 7) * C);

    // thread's lut lines: px = px0 + tid + i*THR; 64B line at fv4 offset
    // px*64 + octet*4. Per-i delta = THR*64 = 65536 fv4.
    const fv4* lbase = (const fv4*)lut
                     + (size_t)(px0 + tid) * (NDET / 2) + octet * 4;

#define LOADPX(A0, A1, A2, A3, I)                                          \
    A0 = __builtin_nontemporal_load(lbase + (size_t)(I) * 65536 + 0);      \
    A1 = __builtin_nontemporal_load(lbase + (size_t)(I) * 65536 + 1);      \
    A2 = __builtin_nontemporal_load(lbase + (size_t)(I) * 65536 + 2);      \
    A3 = __builtin_nontemporal_load(lbase + (size_t)(I) * 65536 + 3);

#define PX_ALL(E0, E1, E2, E3, ACC)                                        \
    pair_accum(lds, 0, E0.x, E0.y, ap0, ACC);                              \
    pair_accum(lds, 1, E0.z, E0.w, ap1, ACC);                              \
    pair_accum(lds, 2, E1.x, E1.y, ap2, ACC);                              \
    pair_accum(lds, 3, E1.z, E1.w, ap3, ACC);                              \
    pair_accum(lds, 4, E2.x, E2.y, ap4, ACC);                              \
    pair_accum(lds, 5, E2.z, E2.w, ap5, ACC);                              \
    pair_accum(lds, 6, E3.x, E3.y, ap6, ACC);                              \
    pair_accum(lds, 7, E3.z, E3.w, ap7, ACC);

    // ---- prologue: px0 + px1 lut lines issued BEFORE the stage copy ----
    fv4 p0, p1, p2, p3, n0, n1, n2, n3;
    LOADPX(p0, p1, p2, p3, 0)
    LOADPX(n0, n1, n2, n3, 1)

    // ---- stage the whole octet: 128KB contiguous, pure uint4 copy ----
    {
        const uint4* src = (const uint4*)(ws16 + (size_t)d0 * NT);
        uint4* dst = (uint4*)lds;
#pragma unroll
        for (int r = 0; r < 8; ++r) dst[tid + r * THR] = src[tid + r * THR];
    }
    __syncthreads();   // the ONLY barrier; drains prologue lut loads too

    fv4 acc0 = {0.f, 0.f, 0.f, 0.f};
    fv4 acc1 = {0.f, 0.f, 0.f, 0.f};
    fv4 acc2 = {0.f, 0.f, 0.f, 0.f};
    fv4 acc3 = {0.f, 0.f, 0.f, 0.f};

    // ---- px0 (ready) ; issue px2 ----
    PX_ALL(p0, p1, p2, p3, acc0)
    LOADPX(p0, p1, p2, p3, 2)

    // ---- px1 (ready) ; issue px3 ----
    PX_ALL(n0, n1, n2, n3, acc1)
    LOADPX(n0, n1, n2, n3, 3)

    // ---- px2: 8 outstanding -> wait until px3's 4 remain ----
    asm volatile("s_waitcnt vmcnt(4)" ::: "memory");
    __builtin_amdgcn_sched_barrier(0);
    PX_ALL(p0, p1, p2, p3, acc2)

    // ---- px3: drain ----
    asm volatile("s_waitcnt vmcnt(0)" ::: "memory");
    __builtin_amdgcn_sched_barrier(0);
    PX_ALL(n0, n1, n2, n3, acc3)

    // ---- emit: 16 octet-blocks accumulate per output ----
    const float inv_norm = 1.0f / 63.5f;               // sum(apod) == 63.5 exactly
#define EMIT(ACC, I)                                                       \
    {                                                                      \
        const int px = px0 + tid + (I) * THR;                              \
        atomicAdd(&out[px],             ACC.x * inv_norm);                 \
        atomicAdd(&out[NPIX + px],      ACC.y * inv_norm);                 \
        atomicAdd(&out[2 * NPIX + px],  ACC.z * inv_norm);                 \
        atomicAdd(&out[3 * NPIX + px],  ACC.w * inv_norm);                 \
    }
    EMIT(acc0, 0)
    EMIT(acc1, 1)
    EMIT(acc2, 2)
    EMIT(acc3, 3)
#undef EMIT
#undef PX_ALL
#undef LOADPX
}

// ---- fallback (ws too small): fp32 staging + cvt in-kernel ----
__global__ __launch_bounds__(512, 4)
void bp_fallback(const float* __restrict__ sino,
                 const float* __restrict__ lut,
                 float* __restrict__ out) {
    __shared__ __half2 lds[4][NT];
    const int tid   = threadIdx.x;
    const int octet = blockIdx.x & 15;
    const int tile  = blockIdx.x >> 4;
    const int d0    = octet * 8;
    const int px0   = tile * 1024;
    float apod[8];
#pragma unroll
    for (int j = 0; j < 8; ++j) {
        float x = (float)(d0 + j) * (6.28318530717958647692f / 127.0f);
        apod[j] = 0.5f - 0.5f * __cosf(x);
    }
    float4 L[2][4];
#pragma unroll
    for (int i = 0; i < 2; ++i) {
        const float4* lq = (const float4*)
            (lut + ((size_t)(px0 + tid + i * 512) * NDET + d0) * 2);
#pragma unroll
        for (int q = 0; q < 4; ++q) L[i][q] = lq[q];
    }
    float acc[2][NB];
#pragma unroll
    for (int i = 0; i < 2; ++i)
#pragma unroll
        for (int b = 0; b < NB; ++b) acc[i][b] = 0.0f;
    const float4* s4 = (const float4*)sino;
    for (int ph = 0; ph < 4; ++ph) {
        const int b0  = (ph >> 1) * 2;
        const int dh  = ph & 1;
        const int dg0 = d0 + dh * 4;
        if (ph) __syncthreads();
        for (int f = tid; f < 4 * (NT / 4); f += 512) {
            int dl = f >> 9;
            int t4 = f & 511;
            size_t row = ((size_t)b0 * NDET + dg0 + dl) * (NT / 4) + t4;
            float4 ve = s4[row];
            float4 vo = s4[row + (size_t)NDET * (NT / 4)];
            __half2* dstp = &lds[dl][t4 * 4];
            dstp[0] = __floats2half2_rn(ve.x, vo.x);
            dstp[1] = __floats2half2_rn(ve.y, vo.y);
            dstp[2] = __floats2half2_rn(ve.z, vo.z);
            dstp[3] = __floats2half2_rn(ve.w, vo.w);
        }
        __syncthreads();
#pragma unroll
        for (int i = 0; i < 2; ++i) {
#pragma unroll
            for (int q2 = 0; q2 < 2; ++q2) {
                float4 Lq = L[i][dh * 2 + q2];
#pragma unroll
                for (int h = 0; h < 2; ++h) {
                    float kf = h ? Lq.z : Lq.x;
                    float af = h ? Lq.w : Lq.y;
                    int   dl = q2 * 2 + h;
                    int k = (int)kf;
                    bool valid = (unsigned)k < (unsigned)(NT - 1);
                    float w  = valid ? apod[dh * 4 + dl] : 0.0f;
                    int  k0  = valid ? k : 0;
                    __half2 s0v = lds[dl][k0];
                    __half2 s1v = lds[dl][k0 + 1];
                    __half2 a2  = __float2half2_rn(af);
                    __half2 sk  = __hfma2(a2, __hsub2(s1v, s0v), s0v);
                    float2  fv  = __half22float2(sk);
                    acc[i][b0 + 0] = fmaf(w, fv.x, acc[i][b0 + 0]);
                    acc[i][b0 + 1] = fmaf(w, fv.y, acc[i][b0 + 1]);
                }
            }
        }
    }
    const float inv_norm = 1.0f / 63.5f;
#pragma unroll
    for (int i = 0; i < 2; ++i) {
        const int px = px0 + tid + i * 512;
#pragma unroll
        for (int b = 0; b < NB; ++b)
            atomicAdd(&out[(size_t)b * NPIX + px], acc[i][b] * inv_norm);
    }
}

extern "C" void kernel_launch(void* const* d_in, const int* in_sizes, int n_in,
                              void* d_out, int out_size, void* d_ws, size_t ws_size,
                              hipStream_t stream) {
    const float* sino = (const float*)d_in[0];
    const float* lut  = (const float*)d_in[1];
    float* out = (float*)d_out;

    (void)hipMemsetAsync(d_out, 0, (size_t)out_size * sizeof(float), stream);

    const size_t ws_needed = (size_t)NDET * NT * sizeof(uint2);   // 2 MB
    if (ws_size >= ws_needed) {
        uint2* ws16 = (uint2*)d_ws;
        cvt_kernel<<<dim3(NDET * NT / 256), dim3(256), 0, stream>>>(sino, ws16);
        // 16 octets x 16 tiles = 256 blocks x 1024 thr = exactly 1 block/CU
        bp_oct<<<dim3(256), dim3(THR), 0, stream>>>(ws16, lut, out);
    } else {
        bp_fallback<<<dim3(1024), dim3(512), 0, stream>>>(sino, lut, out);
    }
}